// Round 14
// baseline (83.772 us; speedup 1.0000x reference)
//
#include <hip/hip_runtime.h>
#include <hip/hip_bf16.h>
#include <stdint.h>

// Problem constants
#define B_  64
#define C_  3
#define H_  512
#define W_  512
#define OC_ 16
#define OH_ 510
#define OW_ 510

// Tile geometry: 256-thread block -> 64(x) x 16(y) outputs; wave wv owns rows
// 4wv..4wv+3; per wave 16 MFMA sets (4 rows x 4 sx), 2 MFMAs per set (K=36).
#define TX_ 64
#define TY_ 16
#define TILES_X_ 8    // ceil(510/64)
#define TILES_Y_ 32   // ceil(510/16)
#define SMH_ 18       // value rows per channel (TY+2)
#define PXW_ 68       // u32 pair slots per row (x=0..67; reads reach x=65)

typedef __attribute__((ext_vector_type(8))) short bf16x8;   // MFMA A/B frag
typedef __attribute__((ext_vector_type(4))) float f32x4;    // MFMA C/D frag

// NaN-safe tanh: 1 - 2/(e^{2x}+1); e=inf -> 1 (no inf/inf NaN).
__device__ __forceinline__ float fast_tanh(float v) {
    float e = __expf(2.0f * v);
    return 1.0f - 2.0f * __builtin_amdgcn_rcpf(e + 1.0f);
}
__device__ __forceinline__ uint16_t bf16u(float f) {
    __hip_bfloat16 h = __float2bfloat16(f);   // RNE
    return __builtin_bit_cast(uint16_t, h);
}
__device__ __forceinline__ uint32_t pack2bf(float v0, float v1) {
    return (uint32_t)bf16u(v0) | ((uint32_t)bf16u(v1) << 16);
}

// Row ids R = c*3+ky (0..8). Bank-balanced slot assignment (bank base mod 32
// of row R is 4*(c*18+ky) mod 32):
//   slot0 rows per g: {0:bank0, 5:16, 1:4, 7:20} -> 2 lanes/bank (free)
//   slot1 rows per g: {2:8, 3:8, 4:12, 6:16}     -> ~2.75-way
// B reg j: j0=slot0+xs0, j1=slot0+xs2, j2=slot1+xs0, j3=slot1+xs2; k=8g+2j+h.
// MFMA2: R=8 (c2ky2) at g==0 slots; B-side wave-broadcast (free).

// ---- prep kernel: bake permuted A-fragments + bias into ws (3 KB) ----
// ws layout: [0) wf1 u16[64][8]; [1024) wf2 u16[64][8]; [2048) bias f32[64][4]
__global__ void conv_prep(const float* __restrict__ wgt,
                          const float* __restrict__ bias,
                          uint16_t* __restrict__ ws16) {
    const int lane = threadIdx.x;        // 0..63
    const int oc = lane & 15, g = lane >> 4;
    const int R0 = (g == 1) ? 5 : (g == 2) ? 1 : (g == 3) ? 7 : 0;
    const int R1 = (g == 1) ? 3 : (g == 2) ? 4 : (g == 3) ? 6 : 2;
    #pragma unroll
    for (int e = 0; e < 8; ++e) {
        int j = e >> 1, h = e & 1;
        int R  = (j < 2) ? R0 : R1;
        int kx = ((j & 1) << 1) + h;          // xs + h
        float w = (kx < 3) ? wgt[oc * 27 + 3 * R + kx] : 0.0f;
        ws16[lane * 8 + e] = bf16u(w);
        float w2 = 0.0f;
        if (g == 0 && e < 4 && kx < 3) w2 = wgt[oc * 27 + 24 + kx];  // R=8
        ws16[512 + lane * 8 + e] = bf16u(w2);
    }
    float* bv = (float*)(ws16 + 1024);
    #pragma unroll
    for (int r = 0; r < 4; ++r) bv[lane * 4 + r] = bias[g * 4 + r];
}

__global__ __launch_bounds__(256)
void conv3x3_min_tanh_mfma(const float* __restrict__ x,
                           const uint4* __restrict__ wsv,
                           float* __restrict__ out) {
    __shared__ uint32_t px[C_ * SMH_ * PXW_];   // 3672 u32 = 14688 B

    const int blk = blockIdx.x;
    const int bx = blk % TILES_X_;
    const int by = (blk / TILES_X_) % TILES_Y_;
    const int b  = blk / (TILES_X_ * TILES_Y_);
    const int ox0 = bx * TX_;
    const int oy0 = by * TY_;

    const int tid  = threadIdx.x;
    const int lane = tid & 63;
    const int wv   = tid >> 6;
    const int nf   = lane & 15;
    const int g    = lane >> 4;

    const float* xb = x + (size_t)b * (C_ * H_ * W_);

    // ---- staging: float4 + 1 scalar -> 4 packed pairs -> ds_write_b128 ----
    {
        const int x0   = 4 * (tid & 15);
        const int rgrp = tid >> 4;          // 0..15
        #pragma unroll
        for (int pass = 0; pass < 4; ++pass) {
            int rg = pass * 16 + rgrp;      // 0..63
            if (rg < C_ * SMH_) {
                int c  = (rg >= SMH_) + (rg >= 2 * SMH_);
                int rr = rg - SMH_ * c;
                int gy = min(oy0 + rr, H_ - 1);
                const float* xrow = xb + (c * H_ + gy) * W_;
                float4 v = *(const float4*)(xrow + ox0 + x0);       // 16B-aligned
                float  v4 = xrow[min(ox0 + x0 + 4, W_ - 1)];
                uint4 pk;
                pk.x = pack2bf(v.x, v.y);
                pk.y = pack2bf(v.y, v.z);
                pk.z = pack2bf(v.z, v.w);
                pk.w = pack2bf(v.w, v4);
                *reinterpret_cast<uint4*>(&px[rg * PXW_ + x0]) = pk;  // b128, aligned
            }
        }
        // extras: pairs x=64,65 per (c,r): 108 single-shot items
        if (tid < C_ * SMH_ * 2) {
            int c   = (tid >= 36) + (tid >= 72);
            int rem = tid - 36 * c;
            int r   = rem >> 1;
            int xx  = 64 + (rem & 1);
            int gy  = min(oy0 + r, H_ - 1);
            const float* xrow = xb + (c * H_ + gy) * W_;
            float v0 = xrow[min(ox0 + xx,     W_ - 1)];
            float v1 = xrow[min(ox0 + xx + 1, W_ - 1)];
            px[(c * SMH_ + r) * PXW_ + xx] = pack2bf(v0, v1);
        }
    }

    // ---- baked fragments (coalesced dwordx4; L2/L3-hot, 3 KB total) ----
    bf16x8 wf1 = __builtin_bit_cast(bf16x8, wsv[lane]);
    bf16x8 wf2 = __builtin_bit_cast(bf16x8, wsv[64 + lane]);
    f32x4  bi  = __builtin_bit_cast(f32x4,  wsv[128 + lane]);

    // ---- loop-invariant slot bases (u32 elems); RL = c*18+ky of slot row ----
    const int rl0 = (g == 1) ? 20 : (g == 2) ? 1  : (g == 3) ? 37 : 0;   // rows {0,5,1,7}
    const int rl1 = (g == 1) ? 18 : (g == 2) ? 19 : (g == 3) ? 36 : 2;   // rows {2,3,4,6}
    const int base0 = (rl0 + 4 * wv) * PXW_ + nf;
    const int base1 = (rl1 + 4 * wv) * PXW_ + nf;
    const int base2 = (38  + 4 * wv) * PXW_ + nf;   // R=8: c2ky2 (broadcast)
    const int baddr = (lane ^ 32) << 2;             // hoisted ds_bpermute address

    __syncthreads();

    // ================= Phase A: all 16 sets -> named scalar mins ==========
    // (named scalars + compile-time offsets only: rule-#20-safe)
#define SET_MIN(row, sx, DEST)                                                 \
    {                                                                          \
        const int off = (row) * PXW_ + (sx) * 16;                              \
        uint32_t r0 = px[base0 + off];                                         \
        uint32_t r1 = px[base0 + off + 2];                                     \
        uint32_t r2 = px[base1 + off];                                         \
        uint32_t r3 = px[base1 + off + 2];                                     \
        bf16x8 tf1 = __builtin_bit_cast(bf16x8, uint4{r0, r1, r2, r3});        \
        uint32_t s0 = px[base2 + off];                                         \
        uint32_t s1 = px[base2 + off + 2];                                     \
        bf16x8 tf2 = __builtin_bit_cast(bf16x8, uint4{s0, s1, 0u, 0u});        \
        f32x4 acc = __builtin_amdgcn_mfma_f32_16x16x32_bf16(wf1, tf1, bi, 0, 0, 0); \
        acc = __builtin_amdgcn_mfma_f32_16x16x32_bf16(wf2, tf2, acc, 0, 0, 0); \
        DEST = fminf(fminf(acc[0], acc[1]), fminf(acc[2], acc[3]));            \
    }

    float m00, m01, m02, m03, m10, m11, m12, m13;
    float m20, m21, m22, m23, m30, m31, m32, m33;
    SET_MIN(0, 0, m00) SET_MIN(0, 1, m01) SET_MIN(0, 2, m02) SET_MIN(0, 3, m03)
    SET_MIN(1, 0, m10) SET_MIN(1, 1, m11) SET_MIN(1, 2, m12) SET_MIN(1, 3, m13)
    SET_MIN(2, 0, m20) SET_MIN(2, 1, m21) SET_MIN(2, 2, m22) SET_MIN(2, 3, m23)
    SET_MIN(3, 0, m30) SET_MIN(3, 1, m31) SET_MIN(3, 2, m32) SET_MIN(3, 3, m33)
#undef SET_MIN

    // ======= Phase B: 16 independent xor16 swizzles (latency amortized) ====
#define SWZ16(M)                                                               \
    {                                                                          \
        int sw_ = __builtin_amdgcn_ds_swizzle(__builtin_bit_cast(int, M), 0x401F); \
        M = fminf(M, __builtin_bit_cast(float, sw_));                          \
    }
    SWZ16(m00) SWZ16(m01) SWZ16(m02) SWZ16(m03)
    SWZ16(m10) SWZ16(m11) SWZ16(m12) SWZ16(m13)
    SWZ16(m20) SWZ16(m21) SWZ16(m22) SWZ16(m23)
    SWZ16(m30) SWZ16(m31) SWZ16(m32) SWZ16(m33)
#undef SWZ16

    // ======= Phase C: per row, select-before-bpermute xor32 + tanh + store ==
    const size_t orow0 = ((size_t)b * OH_ + (oy0 + 4 * wv)) * OW_ + ox0;
    const int oxl = ox0 + lane;

#define ROW_OUT(row, MA, MB, MC, MD)                                           \
    {                                                                          \
        float a_ = MA;                                                         \
        a_ = (g == 1) ? MB : a_;                                               \
        a_ = (g == 2) ? MC : a_;                                               \
        a_ = (g == 3) ? MD : a_;                                               \
        float c_ = MC;                                                         \
        c_ = (g == 1) ? MD : c_;                                               \
        c_ = (g == 2) ? MA : c_;                                               \
        c_ = (g == 3) ? MB : c_;                                               \
        int bp_ = __builtin_amdgcn_ds_bpermute(baddr, __builtin_bit_cast(int, c_)); \
        float mm_ = fminf(a_, __builtin_bit_cast(float, bp_));                 \
        float t_ = fast_tanh(fast_tanh(mm_));                                  \
        int oy_ = oy0 + 4 * wv + (row);                                        \
        if (oy_ < OH_ && oxl < OW_)                                            \
            out[orow0 + (size_t)(row) * OW_ + lane] = t_;                      \
    }
    ROW_OUT(0, m00, m01, m02, m03)
    ROW_OUT(1, m10, m11, m12, m13)
    ROW_OUT(2, m20, m21, m22, m23)
    ROW_OUT(3, m30, m31, m32, m33)
#undef ROW_OUT
}

extern "C" void kernel_launch(void* const* d_in, const int* in_sizes, int n_in,
                              void* d_out, int out_size, void* d_ws, size_t ws_size,
                              hipStream_t stream) {
    const float* x    = (const float*)d_in[0];
    const float* wgt  = (const float*)d_in[1];
    const float* bias = (const float*)d_in[2];
    float* out = (float*)d_out;

    conv_prep<<<1, 64, 0, stream>>>(wgt, bias, (uint16_t*)d_ws);
    conv3x3_min_tanh_mfma<<<dim3(B_ * TILES_X_ * TILES_Y_), 256, 0, stream>>>(
        x, (const uint4*)d_ws, out);
}

// Round 15
// 80.334 us; speedup vs baseline: 1.0428x; 1.0428x over previous
//
#include <hip/hip_runtime.h>
#include <hip/hip_bf16.h>
#include <stdint.h>

// Problem constants
#define B_  64
#define C_  3
#define H_  512
#define W_  512
#define OC_ 16
#define OH_ 510
#define OW_ 510

// Tile: 256-thread block -> 64(x) x 16(y); wave wv owns rows 4wv..4wv+3.
// Per wave: 4 groups (2 rows x 32 px), 3 MFMA 32x32x16 each (one per channel).
// M=32 = 16 oc x 2 output rows (v); K=16 = 4 window rows x {kx01-pair, kx2-pair}.
#define TX_ 64
#define TY_ 16
#define TILES_X_ 8    // ceil(510/64)
#define TILES_Y_ 32   // ceil(510/16)
#define SMH_ 18       // value rows per channel (TY+2)
#define PXW_ 68       // u32 pair slots per row (x=0..67; reads reach x=65)

typedef __attribute__((ext_vector_type(8)))  short bf16x8;   // MFMA A/B frag
typedef __attribute__((ext_vector_type(16))) float f32x16;   // MFMA C/D frag

// NaN-safe tanh: 1 - 2/(e^{2x}+1); e=inf -> 1 (no inf/inf NaN).
__device__ __forceinline__ float fast_tanh(float v) {
    float e = __expf(2.0f * v);
    return 1.0f - 2.0f * __builtin_amdgcn_rcpf(e + 1.0f);
}
__device__ __forceinline__ uint16_t bf16u(float f) {
    __hip_bfloat16 h = __float2bfloat16(f);   // RNE
    return __builtin_bit_cast(uint16_t, h);
}
__device__ __forceinline__ uint32_t pack2bf(float v0, float v1) {
    return (uint32_t)bf16u(v0) | ((uint32_t)bf16u(v1) << 16);
}

// ---- prep kernel: bake A-frags (3 ch) + per-lane bias C-init into ws ----
// ws: [0)    A  u16[3][64][8]   (3072 B)
//     [3072) bias f32[64][16]   (4096 B)
// A[m=(oc,v)][k]: k -> pair p=k>>1, h=k&1; wr=p>>1, pk=p&1;
// kx = pk ? (h? INVALID : 2) : h; ky = wr - v; w = wgt[oc][c][ky][kx] or 0.
__global__ void conv_prep(const float* __restrict__ wgt,
                          const float* __restrict__ bias,
                          uint16_t* __restrict__ ws16) {
    const int lane = threadIdx.x;        // 0..63
    const int mr = lane & 31;
    const int oc = mr & 15, v = mr >> 4;
    const int kc = lane >> 5;
    #pragma unroll
    for (int c = 0; c < C_; ++c)
        #pragma unroll
        for (int e = 0; e < 8; ++e) {
            int k  = 8 * kc + e, p = k >> 1, h = k & 1;
            int wr = p >> 1, pk = p & 1;
            int kx = pk ? (h ? -1 : 2) : h;
            int ky = wr - v;
            float w = 0.0f;
            if (kx >= 0 && ky >= 0 && ky <= 2)
                w = wgt[oc * 27 + c * 9 + ky * 3 + kx];
            ws16[(c * 64 + lane) * 8 + e] = bf16u(w);
        }
    // bias C-init: D row = (reg&3) + 8*(reg>>2) + 4*hi -> oc = row&15
    float* bp_ = (float*)(ws16 + 1536);  // byte offset 3072
    const int hi = lane >> 5;
    #pragma unroll
    for (int reg = 0; reg < 16; ++reg) {
        int row = (reg & 3) + 8 * (reg >> 2) + 4 * hi;
        bp_[lane * 16 + reg] = bias[row & 15];
    }
}

__global__ __launch_bounds__(256)
void conv3x3_min_tanh_mfma(const float* __restrict__ x,
                           const uint4* __restrict__ wsv,
                           float* __restrict__ out) {
    __shared__ uint32_t px[C_ * SMH_ * PXW_];   // 3672 u32 = 14688 B

    const int blk = blockIdx.x;
    const int bx = blk % TILES_X_;
    const int by = (blk / TILES_X_) % TILES_Y_;
    const int b  = blk / (TILES_X_ * TILES_Y_);
    const int ox0 = bx * TX_;
    const int oy0 = by * TY_;

    const int tid  = threadIdx.x;
    const int lane = tid & 63;
    const int wv   = tid >> 6;
    const int pcol = lane & 31;          // B: pixel col ; also M-row&31 unused
    const int hi   = lane >> 5;          // k-chunk AND output-row select v

    const float* xb = x + (size_t)b * (C_ * H_ * W_);

    // ---- staging (R13-verified): float4 -> 4 packed pairs -> ds_write_b128 --
    {
        const int x0   = 4 * (tid & 15);
        const int rgrp = tid >> 4;          // 0..15
        #pragma unroll
        for (int pass = 0; pass < 4; ++pass) {
            int rg = pass * 16 + rgrp;      // 0..63
            if (rg < C_ * SMH_) {
                int c  = (rg >= SMH_) + (rg >= 2 * SMH_);
                int rr = rg - SMH_ * c;
                int gy = min(oy0 + rr, H_ - 1);
                const float* xrow = xb + (c * H_ + gy) * W_;
                float4 v4 = *(const float4*)(xrow + ox0 + x0);      // 16B-aligned
                float  v5 = xrow[min(ox0 + x0 + 4, W_ - 1)];
                uint4 pk;
                pk.x = pack2bf(v4.x, v4.y);
                pk.y = pack2bf(v4.y, v4.z);
                pk.z = pack2bf(v4.z, v4.w);
                pk.w = pack2bf(v4.w, v5);
                *reinterpret_cast<uint4*>(&px[rg * PXW_ + x0]) = pk;
            }
        }
        if (tid < C_ * SMH_ * 2) {          // extras x=64,65
            int c   = (tid >= 36) + (tid >= 72);
            int rem = tid - 36 * c;
            int r   = rem >> 1;
            int xx  = 64 + (rem & 1);
            int gy  = min(oy0 + r, H_ - 1);
            const float* xrow = xb + (c * H_ + gy) * W_;
            float v0 = xrow[min(ox0 + xx,     W_ - 1)];
            float v1 = xrow[min(ox0 + xx + 1, W_ - 1)];
            px[(c * SMH_ + r) * PXW_ + xx] = pack2bf(v0, v1);
        }
    }

    // ---- baked A-frags + bias C-init (7 coalesced dwordx4, L2/L3-hot) ----
    bf16x8 wfA0 = __builtin_bit_cast(bf16x8, wsv[0 * 64 + lane]);
    bf16x8 wfA1 = __builtin_bit_cast(bf16x8, wsv[1 * 64 + lane]);
    bf16x8 wfA2 = __builtin_bit_cast(bf16x8, wsv[2 * 64 + lane]);
    typedef __attribute__((ext_vector_type(4))) float f32x4;
    f32x4 bq0 = __builtin_bit_cast(f32x4, wsv[192 + lane * 4 + 0]);
    f32x4 bq1 = __builtin_bit_cast(f32x4, wsv[192 + lane * 4 + 1]);
    f32x4 bq2 = __builtin_bit_cast(f32x4, wsv[192 + lane * 4 + 2]);
    f32x4 bq3 = __builtin_bit_cast(f32x4, wsv[192 + lane * 4 + 3]);
    f32x16 biasv;
    biasv[0]  = bq0[0]; biasv[1]  = bq0[1]; biasv[2]  = bq0[2]; biasv[3]  = bq0[3];
    biasv[4]  = bq1[0]; biasv[5]  = bq1[1]; biasv[6]  = bq1[2]; biasv[7]  = bq1[3];
    biasv[8]  = bq2[0]; biasv[9]  = bq2[1]; biasv[10] = bq2[2]; biasv[11] = bq2[3];
    biasv[12] = bq3[0]; biasv[13] = bq3[1]; biasv[14] = bq3[2]; biasv[15] = bq3[3];

    // ---- per-lane B bases: window rows 2*hi, 2*hi+1 of group base row ----
    const int bC0 = (0 * SMH_ + 4 * wv + 2 * hi) * PXW_ + pcol;
    const int bC1 = (1 * SMH_ + 4 * wv + 2 * hi) * PXW_ + pcol;
    const int bC2 = (2 * SMH_ + 4 * wv + 2 * hi) * PXW_ + pcol;
    const int baddr = (lane ^ 32) << 2;   // hoisted ds_bpermute address

    __syncthreads();

    const size_t obase = ((size_t)b * OH_ + (oy0 + 4 * wv)) * OW_ + ox0;

    // ---- 4 groups: gi = row-pair (0,1), xh = x-half (0,1) ----
#define GROUP(gi, xh)                                                          \
    {                                                                          \
        const int offs = (gi) * (2 * PXW_) + 32 * (xh);                        \
        uint32_t a0 = px[bC0 + offs];                                          \
        uint32_t a1 = px[bC0 + offs + 2];                                      \
        uint32_t a2 = px[bC0 + offs + PXW_];                                   \
        uint32_t a3 = px[bC0 + offs + PXW_ + 2];                               \
        bf16x8 tb0 = __builtin_bit_cast(bf16x8, uint4{a0, a1, a2, a3});        \
        uint32_t b0 = px[bC1 + offs];                                          \
        uint32_t b1 = px[bC1 + offs + 2];                                      \
        uint32_t b2 = px[bC1 + offs + PXW_];                                   \
        uint32_t b3 = px[bC1 + offs + PXW_ + 2];                               \
        bf16x8 tb1 = __builtin_bit_cast(bf16x8, uint4{b0, b1, b2, b3});        \
        uint32_t c0 = px[bC2 + offs];                                          \
        uint32_t c1 = px[bC2 + offs + 2];                                      \
        uint32_t c2 = px[bC2 + offs + PXW_];                                   \
        uint32_t c3 = px[bC2 + offs + PXW_ + 2];                               \
        bf16x8 tb2 = __builtin_bit_cast(bf16x8, uint4{c0, c1, c2, c3});        \
        f32x16 acc = __builtin_amdgcn_mfma_f32_32x32x16_bf16(wfA0, tb0, biasv, 0, 0, 0); \
        acc = __builtin_amdgcn_mfma_f32_32x32x16_bf16(wfA1, tb1, acc, 0, 0, 0);\
        acc = __builtin_amdgcn_mfma_f32_32x32x16_bf16(wfA2, tb2, acc, 0, 0, 0);\
        float m0 = fminf(fminf(fminf(acc[0], acc[1]), fminf(acc[2], acc[3])),  \
                         fminf(fminf(acc[4], acc[5]), fminf(acc[6], acc[7]))); \
        float m1 = fminf(fminf(fminf(acc[8], acc[9]), fminf(acc[10], acc[11])),\
                         fminf(fminf(acc[12], acc[13]), fminf(acc[14], acc[15])));\
        float snd = hi ? m0 : m1;   /* partner (hi^1) needs my m_{1-hi} */     \
        int bp = __builtin_amdgcn_ds_bpermute(baddr, __builtin_bit_cast(int, snd)); \
        float own = hi ? m1 : m0;                                              \
        float mm = fminf(own, __builtin_bit_cast(float, bp));                  \
        float t_ = fast_tanh(fast_tanh(mm));                                   \
        int oy = oy0 + 4 * wv + 2 * (gi) + hi;                                 \
        int ox = ox0 + 32 * (xh) + pcol;                                       \
        if (oy < OH_ && ox < OW_)                                              \
            out[obase + (size_t)((2 * (gi) + hi) * OW_ + 32 * (xh) + pcol)] = t_; \
    }

    GROUP(0, 0)
    GROUP(0, 1)
    GROUP(1, 0)
    GROUP(1, 1)
#undef GROUP
}

extern "C" void kernel_launch(void* const* d_in, const int* in_sizes, int n_in,
                              void* d_out, int out_size, void* d_ws, size_t ws_size,
                              hipStream_t stream) {
    const float* x    = (const float*)d_in[0];
    const float* wgt  = (const float*)d_in[1];
    const float* bias = (const float*)d_in[2];
    float* out = (float*)d_out;

    conv_prep<<<1, 64, 0, stream>>>(wgt, bias, (uint16_t*)d_ws);
    conv3x3_min_tanh_mfma<<<dim3(B_ * TILES_X_ * TILES_Y_), 256, 0, stream>>>(
        x, (const uint4*)d_ws, out);
}